// Round 10
// baseline (423.102 us; speedup 1.0000x reference)
//
#include <hip/hip_runtime.h>

#define EPS 1e-12f
#define CAP 32    // ELL slots/vertex. deg ~ Poisson(6); P(deg>=32) ~ 1e-13/vertex
#define CAPU 8    // front-loaded slots; tail (P(deg>8)~0.15/vertex) is cheap

typedef unsigned long long ull;

// ---------------------------------------------------------------------------
// Pipeline (4 launches, split for rocprof visibility):
//   zero cursor -> transpose_in (verts [B][V][3] -> vT [V][3][32] plane-major)
//   -> fill_corner (CIDX: store the 4B corner id, not the 8B (a,b) pair)
//   -> gather_t (batch-interleaved; decode corner -> broadcast faces reads)
//
// r10 KEY CHANGE — minimal-entry fill: the adjacency entry is just the corner
// position t in faces. fill = 1 coalesced 4B read + 1 atomic + 1 PLAIN 4B
// scattered store (plain -> L2 merges ~6 same-vertex entries per 64B line;
// r9's NT 8B stores each paid a separate fabric transaction). Gather decodes
// f=t/3, c=t-3f and reads the two neighbor indices from faces[] as BROADCAST
// loads (same address across the half-wave; faces = 4.8MB, L2-hot).
// Also halves the adjacency footprint 51->26MB: total footprint 287->261MB
// vs 256MB L3 (r9 showed FETCH ~3x cold-miss floor => L3 capacity misses).
//
// Corner t of face f=(i0,i1,i2), c=t-3f: v=faces[t], a=next(c), b=prev(c);
// contribution = (A-v) x (B-v) = reference cross(v2-v1, v0-v1) (cyclic id).
//
// Regime map (r0-r9): gather is HBM-byte-bound at ~3.4 TB/s (FETCH = HBM
// only; L3 capacity-missing). Batch-interleaved rows (B==32==half-wave) give
// 100% line utilization. Guarded scattered loads get re-serialized by the
// compiler -> branch-free clamp (junk slots -> t=0 -> fixed L1-hot rows).
// Partitioned-LDS fill 2x worse than machine-wide atomics (r5).
// ---------------------------------------------------------------------------

__global__ void zero_ints(int* __restrict__ p, int n) {
    int i = blockIdx.x * blockDim.x + threadIdx.x;
    if (i < n) p[i] = 0;
}

// tiled transpose: verts [B][V][3] f32 -> vT [V][3][32] (384B row / vertex).
// PLAIN stores (pre-warm vT into cache hierarchy; it's read ~13x by gather).
__global__ __launch_bounds__(1024) void transpose_in(const float* __restrict__ verts,
                                                     float* __restrict__ vT,
                                                     int V) {
    __shared__ float sx[32][33], sy[32][33], sz[32][33];
    int tx = threadIdx.x & 31, ty = threadIdx.x >> 5;
    int v0 = blockIdx.x * 32;
    const float* p = verts + ((size_t)ty * V + (v0 + tx)) * 3;
    sx[ty][tx] = __builtin_nontemporal_load(p + 0);
    sy[ty][tx] = __builtin_nontemporal_load(p + 1);
    sz[ty][tx] = __builtin_nontemporal_load(p + 2);
    __syncthreads();
    float* o = vT + (size_t)(v0 + ty) * 96;
    o[tx]      = sx[tx][ty];
    o[32 + tx] = sy[tx][ty];
    o[64 + tx] = sz[tx][ty];
}

// one thread per corner: 1 coalesced read + 1 atomic + 1 plain 4B store
__global__ void fill_corner(const int* __restrict__ faces, int* __restrict__ cursor,
                            int* __restrict__ cidx, int E) {
    int t = blockIdx.x * blockDim.x + threadIdx.x;
    if (t >= E) return;
    int iv = faces[t];                       // coalesced: the corner's vertex
    int s = atomicAdd(&cursor[iv], 1);
    if (s < CAP) cidx[iv * CAP + s] = t;     // plain store: L2 line-merge
}

// block = 1024 = 32 vertices x 32 batches; half-wave (32 lanes) = one vertex
__global__ __launch_bounds__(1024) void gather_t(const float* __restrict__ vT,
                                                 const int* __restrict__ deg,
                                                 const int* __restrict__ cidx,
                                                 const int* __restrict__ faces,
                                                 float* __restrict__ out,
                                                 int V) {
    __shared__ float sx[32][33], sy[32][33], sz[32][33];
    int b = threadIdx.x & 31;        // batch
    int vi = threadIdx.x >> 5;       // local vertex
    int v = blockIdx.x * 32 + vi;

    int d = min(deg[v], CAP);        // uniform per half-wave
    const float* crow = vT + (size_t)v * 96;
    float vx = crow[b], vy = crow[32 + b], vz = crow[64 + b];
    const int* cv = cidx + v * CAP;  // contiguous 32B broadcast read
    int e[CAPU];
#pragma unroll
    for (int s = 0; s < CAPU; s++)
        e[s] = cv[s];
    __builtin_amdgcn_sched_barrier(0);

    // decode corner -> neighbor indices via BROADCAST faces reads (L2-hot).
    // junk slots (s>=d) clamp to t=0 -> f=0,c=0 -> fixed L1-hot addresses
    int ian[CAPU], ibn[CAPU];
#pragma unroll
    for (int s = 0; s < CAPU; s++) {
        int t = (s < d) ? e[s] : 0;
        int f = t / 3;               // magic-mul
        int c = t - 3 * f;
        int base = 3 * f;
        ian[s] = faces[base + (c == 2 ? 0 : c + 1)];   // a = next (cyclic)
        ibn[s] = faces[base + (c == 0 ? 2 : c - 1)];   // b = prev (cyclic)
    }
    __builtin_amdgcn_sched_barrier(0);

    // coalesced 384B row loads, branch-free
    float Ax[CAPU], Ay[CAPU], Az[CAPU], Bx[CAPU], By[CAPU], Bz[CAPU];
#pragma unroll
    for (int s = 0; s < CAPU; s++) {
        const float* ra = vT + (size_t)(unsigned)ian[s] * 96;
        const float* rb = vT + (size_t)(unsigned)ibn[s] * 96;
        Ax[s] = ra[b]; Ay[s] = ra[32 + b]; Az[s] = ra[64 + b];
        Bx[s] = rb[b]; By[s] = rb[32 + b]; Bz[s] = rb[64 + b];
    }
    __builtin_amdgcn_sched_barrier(0);

    float ax = 0.f, ay = 0.f, az = 0.f;
#pragma unroll
    for (int s = 0; s < CAPU; s++) {
        if (s < d) {
            float aX = Ax[s] - vx, aY = Ay[s] - vy, aZ = Az[s] - vz;
            float bX = Bx[s] - vx, bY = By[s] - vy, bZ = Bz[s] - vz;
            ax += aY * bZ - aZ * bY;
            ay += aZ * bX - aX * bZ;
            az += aX * bY - aY * bX;
        }
    }
    // tail (deg > CAPU, ~15% of half-waves)
    for (int s = CAPU; s < d; s++) {
        int t = cv[s];
        int f = t / 3;
        int c = t - 3 * f;
        int base = 3 * f;
        int ia = faces[base + (c == 2 ? 0 : c + 1)];
        int ib = faces[base + (c == 0 ? 2 : c - 1)];
        const float* ra = vT + (size_t)(unsigned)ia * 96;
        const float* rb = vT + (size_t)(unsigned)ib * 96;
        float aX = ra[b] - vx, aY = ra[32 + b] - vy, aZ = ra[64 + b] - vz;
        float bX = rb[b] - vx, bY = rb[32 + b] - vy, bZ = rb[64 + b] - vz;
        ax += aY * bZ - aZ * bY;
        ay += aZ * bX - aX * bZ;
        az += aX * bY - aY * bX;
    }

    float scn = rsqrtf(fmaxf(ax * ax + ay * ay + az * az, EPS));
    sx[vi][b] = ax * scn; sy[vi][b] = ay * scn; sz[vi][b] = az * scn;
    __syncthreads();

    // output transpose: lanes b -> contiguous 384B per half-wave; NT stores
    float* o = out + ((size_t)vi * V + (size_t)blockIdx.x * 32 + b) * 3;
    __builtin_nontemporal_store(sx[b][vi], o + 0);
    __builtin_nontemporal_store(sy[b][vi], o + 1);
    __builtin_nontemporal_store(sz[b][vi], o + 2);
}

extern "C" void kernel_launch(void* const* d_in, const int* in_sizes, int n_in,
                              void* d_out, int out_size, void* d_ws, size_t ws_size,
                              hipStream_t stream) {
    const float* verts = (const float*)d_in[0];
    const int* faces = (const int*)d_in[1];
    float* out = (float*)d_out;

    const int V = 200000;                    // divisible by 32
    const int F = in_sizes[1] / 3;           // 400000
    const int B = in_sizes[0] / (3 * V);     // 32 (layout hard-wires B == 32)
    const int E = 3 * F;                     // 1.2M corners
    (void)B;

    // workspace: vT[V*96] f32 (76.8MB) | cursor[V] (0.8MB) | cidx[V*CAP] int
    // (25.6MB) -> 103.2 MB total
    char* w = (char*)d_ws;
    float* vT = (float*)w;  w += (size_t)V * 96 * sizeof(float);
    int* cursor = (int*)w;  w += (size_t)V * sizeof(int);
    int* cidx = (int*)w;

    zero_ints<<<(V + 255) / 256, 256, 0, stream>>>(cursor, V);
    transpose_in<<<V / 32, 1024, 0, stream>>>(verts, vT, V);
    fill_corner<<<(E + 255) / 256, 256, 0, stream>>>(faces, cursor, cidx, E);
    gather_t<<<V / 32, 1024, 0, stream>>>(vT, cursor, cidx, faces, out, V);
}

// Round 11
// 353.241 us; speedup vs baseline: 1.1978x; 1.1978x over previous
//
#include <hip/hip_runtime.h>

#define EPS 1e-12f
#define CAP 32    // ELL slots/vertex. deg ~ Poisson(6); P(deg>=32) ~ 1e-13/vertex
#define CAPU 8    // front-loaded slots; tail (P(deg>8)~0.15/vertex) is cheap

typedef unsigned long long ull;

// ---------------------------------------------------------------------------
// Pipeline (3 launches):
//   zero cursor -> prep (transpose & fill ROLE-INTERLEAVED in block space:
//   every 6th block is a fill block, so the BW-bound transpose co-runs with
//   the latency-bound atomic fill instead of serializing after it)
//   -> gather_t (r9-proven: batch-interleaved plane-major rows, 8B ELL).
//
// r11 changes vs r9 (best: 399us = 168 gather + ~230 prep):
//  - REVERT r10's cidx/faces-indirection (faces decode reads thrash L2 and
//    evict vT: gather +28us, FETCH +73MB).
//  - prep role-interleave: r9's "fused" prep dispatched all 6250 transpose
//    blocks before the 1172 fill blocks -> serial phases. Interleaving gives
//    true overlap; transpose (~35us) hides inside the fill window.
//  - gather: NT loads for deg/ELL (single-use streams; stop evicting the
//    13x-reused vT rows from L2/L3). Fill stores plain 8B (L2-mergeable).
//
// ELL entry (lo=a=next, hi=b=prev, cyclic) at any corner of face (i0,i1,i2);
// contribution = (A-v) x (B-v) = reference cross(v2-v1, v0-v1) (cyclic id).
//
// Regime map (r0-r10): gather is fabric-byte-bound (~3.4-3.7 TB/s L2-miss
// service; dur tracks bytes, r8->r9 confirmed by the 384/512 scaling).
// Batch-interleaved rows (B==32==half-wave) give 100% line utilization.
// Guarded scattered loads get re-serialized by the compiler -> branch-free
// clamp to vertex 0. Partitioned-LDS fill 2x worse than machine-wide atomics.
// ---------------------------------------------------------------------------

__global__ void zero_ints(int* __restrict__ p, int n) {
    int i = blockIdx.x * blockDim.x + threadIdx.x;
    if (i < n) p[i] = 0;
}

// Role-interleaved prep. fblk fill blocks at bid%6==5 (corner-parallel fill:
// 1 coalesced read + rotate-in-triple reads (L1) + 1 atomic + 1 plain 8B
// store); all other blocks: tiled transpose verts [B][V][3] -> vT [V][3][32].
__global__ __launch_bounds__(1024) void prep_kernel(const float* __restrict__ verts,
                                                    float* __restrict__ vT,
                                                    const int* __restrict__ faces,
                                                    int* __restrict__ cursor,
                                                    ull* __restrict__ ell,
                                                    int V, int fblk, int E) {
    __shared__ float sx[32][33], sy[32][33], sz[32][33];
    int bid = blockIdx.x;
    int q = bid / 6, r = bid - 6 * q;
    bool isfill = (r == 5) && (q < fblk);
    if (isfill) {
        int t = q * 1024 + threadIdx.x;
        if (t >= E) return;
        int f = t / 3;               // magic-mul
        int c = t - 3 * f;
        int base = 3 * f;
        int iv = faces[base + c];                      // coalesced
        int ia = faces[base + (c == 2 ? 0 : c + 1)];   // next (cyclic) — same
        int ib = faces[base + (c == 0 ? 2 : c - 1)];   // prev — lines, L1-hot
        int s = atomicAdd(&cursor[iv], 1);
        if (s < CAP) {
            ull e = ((ull)(unsigned)ib << 32) | (unsigned)ia;  // lo=a, hi=b
            ell[(size_t)iv * CAP + s] = e;             // plain: L2 line-merge
        }
    } else {
        int t_id = bid - min(q + (r == 5 ? 1 : 0), fblk);
        int tx = threadIdx.x & 31, ty = threadIdx.x >> 5;
        int v0 = t_id * 32;
        // read: batch ty, vertices v0+tx (contiguous 384B per half-wave)
        const float* p = verts + ((size_t)ty * V + (v0 + tx)) * 3;
        sx[ty][tx] = __builtin_nontemporal_load(p + 0);
        sy[ty][tx] = __builtin_nontemporal_load(p + 1);
        sz[ty][tx] = __builtin_nontemporal_load(p + 2);
        __syncthreads();
        // write: vertex v0+ty, plane-major, batch tx (3x 128B coalesced)
        float* o = vT + (size_t)(v0 + ty) * 96;
        o[tx]      = sx[tx][ty];
        o[32 + tx] = sy[tx][ty];
        o[64 + tx] = sz[tx][ty];
    }
}

// block = 1024 = 32 vertices x 32 batches; half-wave (32 lanes) = one vertex
__global__ __launch_bounds__(1024) void gather_t(const float* __restrict__ vT,
                                                 const int* __restrict__ deg,
                                                 const ull* __restrict__ ell,
                                                 float* __restrict__ out,
                                                 int V) {
    __shared__ float sx[32][33], sy[32][33], sz[32][33];
    int b = threadIdx.x & 31;        // batch
    int vi = threadIdx.x >> 5;       // local vertex
    int v = blockIdx.x * 32 + vi;

    int d = min(__builtin_nontemporal_load(deg + v), CAP);  // single-use: NT
    const float* crow = vT + (size_t)v * 96;
    float vx = crow[b], vy = crow[32 + b], vz = crow[64 + b];  // plain: reused
    const ull* ev = ell + (size_t)v * CAP;          // vertex's slots: one line
    ull e[CAPU];
#pragma unroll
    for (int s = 0; s < CAPU; s++)   // broadcast, single-use stream: NT
        e[s] = __builtin_nontemporal_load(ev + s);
    __builtin_amdgcn_sched_barrier(0);

    // branch-free: invalid slots clamp to vertex 0 -> L1-hot row
    float Ax[CAPU], Ay[CAPU], Az[CAPU], Bx[CAPU], By[CAPU], Bz[CAPU];
#pragma unroll
    for (int s = 0; s < CAPU; s++) {
        unsigned ia = (s < d) ? (unsigned)(e[s] & 0xffffffffull) : 0u;
        unsigned ib = (s < d) ? (unsigned)(e[s] >> 32) : 0u;
        const float* ra = vT + (size_t)ia * 96;     // 3x 128B coalesced
        const float* rb = vT + (size_t)ib * 96;
        Ax[s] = ra[b]; Ay[s] = ra[32 + b]; Az[s] = ra[64 + b];
        Bx[s] = rb[b]; By[s] = rb[32 + b]; Bz[s] = rb[64 + b];
    }
    __builtin_amdgcn_sched_barrier(0);

    float ax = 0.f, ay = 0.f, az = 0.f;
#pragma unroll
    for (int s = 0; s < CAPU; s++) {
        if (s < d) {
            float aX = Ax[s] - vx, aY = Ay[s] - vy, aZ = Az[s] - vz;
            float bX = Bx[s] - vx, bY = By[s] - vy, bZ = Bz[s] - vz;
            ax += aY * bZ - aZ * bY;
            ay += aZ * bX - aX * bZ;
            az += aX * bY - aY * bX;
        }
    }
    // tail (deg > CAPU, ~15% of half-waves): broadcast ELL + coalesced rows
    for (int s = CAPU; s < d; s++) {
        ull cu = __builtin_nontemporal_load(ev + s);
        const float* ra = vT + (size_t)(unsigned)(cu & 0xffffffffull) * 96;
        const float* rb = vT + (size_t)(unsigned)(cu >> 32) * 96;
        float aX = ra[b] - vx, aY = ra[32 + b] - vy, aZ = ra[64 + b] - vz;
        float bX = rb[b] - vx, bY = rb[32 + b] - vy, bZ = rb[64 + b] - vz;
        ax += aY * bZ - aZ * bY;
        ay += aZ * bX - aX * bZ;
        az += aX * bY - aY * bX;
    }

    float scn = rsqrtf(fmaxf(ax * ax + ay * ay + az * az, EPS));
    sx[vi][b] = ax * scn; sy[vi][b] = ay * scn; sz[vi][b] = az * scn;
    __syncthreads();

    // output transpose: lanes b -> contiguous 384B per half-wave; LDS reads
    // stride-33 -> conflict-free; NT stores (never re-read)
    float* o = out + ((size_t)vi * V + (size_t)blockIdx.x * 32 + b) * 3;
    __builtin_nontemporal_store(sx[b][vi], o + 0);
    __builtin_nontemporal_store(sy[b][vi], o + 1);
    __builtin_nontemporal_store(sz[b][vi], o + 2);
}

extern "C" void kernel_launch(void* const* d_in, const int* in_sizes, int n_in,
                              void* d_out, int out_size, void* d_ws, size_t ws_size,
                              hipStream_t stream) {
    const float* verts = (const float*)d_in[0];
    const int* faces = (const int*)d_in[1];
    float* out = (float*)d_out;

    const int V = 200000;                    // divisible by 32
    const int F = in_sizes[1] / 3;           // 400000
    const int B = in_sizes[0] / (3 * V);     // 32 (layout hard-wires B == 32)
    const int E = 3 * F;                     // 1.2M corners
    (void)B;

    // workspace: vT[V*96] f32 (76.8MB) | cursor[V] (0.8MB) | ell[V*CAP] ull
    // (51.2MB) -> 128.8 MB total (154 MB proven to fit)
    char* w = (char*)d_ws;
    float* vT = (float*)w;  w += (size_t)V * 96 * sizeof(float);
    int* cursor = (int*)w;  w += (size_t)V * sizeof(int);
    ull* ell = (ull*)w;

    zero_ints<<<(V + 255) / 256, 256, 0, stream>>>(cursor, V);

    int tblk = V / 32;                       // 6250 transpose blocks
    int fblk = (E + 1023) / 1024;            // 1172 fill blocks
    prep_kernel<<<tblk + fblk, 1024, 0, stream>>>(verts, vT, faces, cursor, ell,
                                                  V, fblk, E);

    gather_t<<<V / 32, 1024, 0, stream>>>(vT, cursor, ell, out, V);
}

// Round 13
// 348.618 us; speedup vs baseline: 1.2137x; 1.0133x over previous
//
#include <hip/hip_runtime.h>

#define EPS 1e-12f
#define CAP 32    // hash-table slots/vertex. deg ~ Poisson(6); P(deg>32) ~ 1e-13
#define CAPU 8    // front-loaded entries; tail (deg>8, ~15% of half-waves) cheap
#define EMPTY 0xFFFFFFFFFFFFFFFFull

typedef unsigned long long ull;

// ---------------------------------------------------------------------------
// Pipeline (3 launches):
//   prep1 (role-interleaved: transpose verts [B][V][3] -> vT [V][3][32]
//          plane-major  ||  clear ELL to EMPTY sentinel, NT 2x8B stores)
//   fill_cas (one 8B atomicCAS open-addressing insert per corner — NO cursor,
//          NO dependent store: merges r11's {atomicAdd + scattered store}
//          two fabric round-trip classes into ONE)
//   gather_t (batch-interleaved; lane-per-slot coalesced 256B ELL read +
//          64-bit ballot -> valid mask; shfl-broadcast entries; no deg array)
//
// r12 theory: fill (~165us in r11, the largest item) is fabric-transaction-
// bound at ~2 transactions/corner; CAS-insert is 1.1 transactions/corner and
// spreads RMWs over 6.4M addresses (vs 6 ops/address on the 200K cursor).
//
// ELL entry (lo=a=next, hi=b=prev, cyclic) at any corner of face (i0,i1,i2);
// contribution = (A-v) x (B-v) = reference cross(v2-v1, v0-v1) (cyclic id).
// e != EMPTY always (hi word < 2^18). Probe start = hash(corner id).
//
// Regime map (r0-r11): gather fabric-byte-bound (~3.4 TB/s; dur tracks
// bytes, r8->r9 384/512 scaling). Batch-interleaved rows (B==32==half-wave)
// = 100% line utilization. Guarded scattered loads get re-serialized by the
// compiler -> branch-free clamp to vertex 0. Partitioned-LDS fill 2x worse
// than machine-wide atomics. faces-indirection in gather thrashes L2 (r10).
// ---------------------------------------------------------------------------

// role-interleaved: bid%3 in {0,1} -> transpose; bid%3==2 -> ELL clear
__global__ __launch_bounds__(1024) void prep1(const float* __restrict__ verts,
                                              float* __restrict__ vT,
                                              ull* __restrict__ ellu,
                                              int V, int nclr) {
    __shared__ float sx[32][33], sy[32][33], sz[32][33];
    int bid = blockIdx.x;
    int q = bid / 3, r = bid - 3 * q;
    if (r == 2) {                    // clear: 2x 8B NT stores (16B/thread)
        int idx = q * 1024 + threadIdx.x;
        if (idx < nclr) {
            __builtin_nontemporal_store(EMPTY, ellu + 2 * (size_t)idx);
            __builtin_nontemporal_store(EMPTY, ellu + 2 * (size_t)idx + 1);
        }
    } else {                         // transpose block t_id in [0, V/32)
        int t_id = q * 2 + r;
        int tx = threadIdx.x & 31, ty = threadIdx.x >> 5;
        int v0 = t_id * 32;
        const float* p = verts + ((size_t)ty * V + (v0 + tx)) * 3;
        sx[ty][tx] = __builtin_nontemporal_load(p + 0);
        sy[ty][tx] = __builtin_nontemporal_load(p + 1);
        sz[ty][tx] = __builtin_nontemporal_load(p + 2);
        __syncthreads();
        float* o = vT + (size_t)(v0 + ty) * 96;
        o[tx]      = sx[tx][ty];
        o[32 + tx] = sy[tx][ty];
        o[64 + tx] = sz[tx][ty];
    }
}

// one thread per corner: ONE atomicCAS insert (open addressing, probe start
// hashed from corner id so same-vertex corners start at different slots)
__global__ void fill_cas(const int* __restrict__ faces, ull* __restrict__ ell,
                         int E) {
    int t = blockIdx.x * blockDim.x + threadIdx.x;
    if (t >= E) return;
    int f = t / 3;               // magic-mul
    int c = t - 3 * f;
    int base = 3 * f;
    int iv = faces[base + c];                      // coalesced
    int ia = faces[base + (c == 2 ? 0 : c + 1)];   // next (cyclic)
    int ib = faces[base + (c == 0 ? 2 : c - 1)];   // prev (cyclic)
    ull e = ((ull)(unsigned)ib << 32) | (unsigned)ia;
    ull* bp = ell + (size_t)iv * CAP;
    unsigned h = ((unsigned)t * 2654435761u) >> 27;   // 5-bit probe start
#pragma unroll 4
    for (int k = 0; k < CAP; k++) {
        unsigned p = (h + k) & (CAP - 1);
        if (atomicCAS(bp + p, EMPTY, e) == EMPTY) break;
    }
}

// block = 1024 = 32 vertices x 32 batches; half-wave (32 lanes) = one vertex
__global__ __launch_bounds__(1024) void gather_t(const float* __restrict__ vT,
                                                 const ull* __restrict__ ell,
                                                 float* __restrict__ out,
                                                 int V) {
    __shared__ float sx[32][33], sy[32][33], sz[32][33];
    int b = threadIdx.x & 31;        // batch / slot id
    int vi = threadIdx.x >> 5;       // local vertex
    int v = blockIdx.x * 32 + vi;
    int half = (threadIdx.x & 63) >> 5;   // which half of the wave

    // lane-per-slot coalesced 256B read of this vertex's 32 slots (single-use)
    ull eln = __builtin_nontemporal_load(ell + (size_t)v * CAP + b);
    unsigned lo = (unsigned)eln, hi = (unsigned)(eln >> 32);
    ull full = __ballot(eln != EMPTY);
    unsigned mask = (unsigned)(full >> (half * 32));   // this half-wave's mask
    int d = __popc(mask);                              // true degree

    const float* crow = vT + (size_t)v * 96;
    float vx = crow[b], vy = crow[32 + b], vz = crow[64 + b];

    // extract first CAPU valid slot-lanes (mask is half-wave-uniform)
    unsigned m = mask;
    int ia[CAPU], ib[CAPU];
#pragma unroll
    for (int j = 0; j < CAPU; j++) {
        int l = m ? (__ffs(m) - 1) : 0;
        m &= m - 1;
        int src = half * 32 + l;
        int lj = __shfl((int)lo, src);
        int hj = __shfl((int)hi, src);
        ia[j] = (j < d) ? lj : 0;    // clamp junk -> vertex 0 (L1-hot row)
        ib[j] = (j < d) ? hj : 0;
    }
    __builtin_amdgcn_sched_barrier(0);

    // branch-free coalesced 384B row loads
    float Ax[CAPU], Ay[CAPU], Az[CAPU], Bx[CAPU], By[CAPU], Bz[CAPU];
#pragma unroll
    for (int j = 0; j < CAPU; j++) {
        const float* ra = vT + (size_t)(unsigned)ia[j] * 96;
        const float* rb = vT + (size_t)(unsigned)ib[j] * 96;
        Ax[j] = ra[b]; Ay[j] = ra[32 + b]; Az[j] = ra[64 + b];
        Bx[j] = rb[b]; By[j] = rb[32 + b]; Bz[j] = rb[64 + b];
    }
    __builtin_amdgcn_sched_barrier(0);

    float ax = 0.f, ay = 0.f, az = 0.f;
#pragma unroll
    for (int j = 0; j < CAPU; j++) {
        if (j < d) {
            float aX = Ax[j] - vx, aY = Ay[j] - vy, aZ = Az[j] - vz;
            float bX = Bx[j] - vx, bY = By[j] - vy, bZ = Bz[j] - vz;
            ax += aY * bZ - aZ * bY;
            ay += aZ * bX - aX * bZ;
            az += aX * bY - aY * bX;
        }
    }
    // tail (deg > CAPU, ~15% of half-waves)
    for (int j = CAPU; j < d; j++) {
        int l = __ffs(m) - 1;
        m &= m - 1;
        int src = half * 32 + l;
        int lj = __shfl((int)lo, src);
        int hj = __shfl((int)hi, src);
        const float* ra = vT + (size_t)(unsigned)lj * 96;
        const float* rb = vT + (size_t)(unsigned)hj * 96;
        float aX = ra[b] - vx, aY = ra[32 + b] - vy, aZ = ra[64 + b] - vz;
        float bX = rb[b] - vx, bY = rb[32 + b] - vy, bZ = rb[64 + b] - vz;
        ax += aY * bZ - aZ * bY;
        ay += aZ * bX - aX * bZ;
        az += aX * bY - aY * bX;
    }

    float scn = rsqrtf(fmaxf(ax * ax + ay * ay + az * az, EPS));
    sx[vi][b] = ax * scn; sy[vi][b] = ay * scn; sz[vi][b] = az * scn;
    __syncthreads();

    // output transpose: lanes b -> contiguous 384B per half-wave; LDS reads
    // stride-33 -> conflict-free; NT stores (never re-read)
    float* o = out + ((size_t)vi * V + (size_t)blockIdx.x * 32 + b) * 3;
    __builtin_nontemporal_store(sx[b][vi], o + 0);
    __builtin_nontemporal_store(sy[b][vi], o + 1);
    __builtin_nontemporal_store(sz[b][vi], o + 2);
}

extern "C" void kernel_launch(void* const* d_in, const int* in_sizes, int n_in,
                              void* d_out, int out_size, void* d_ws, size_t ws_size,
                              hipStream_t stream) {
    const float* verts = (const float*)d_in[0];
    const int* faces = (const int*)d_in[1];
    float* out = (float*)d_out;

    const int V = 200000;                    // divisible by 32
    const int F = in_sizes[1] / 3;           // 400000
    const int B = in_sizes[0] / (3 * V);     // 32 (layout hard-wires B == 32)
    const int E = 3 * F;                     // 1.2M corners
    (void)B;

    // workspace: vT[V*96] f32 (76.8MB) | ell[V*CAP] ull (51.2MB) -> 128 MB
    char* w = (char*)d_ws;
    float* vT = (float*)w;  w += (size_t)V * 96 * sizeof(float);
    ull* ell = (ull*)w;

    int tblk = V / 32;                       // 6250 transpose blocks
    int nclr = (int)((size_t)V * CAP / 2);   // 3.2M x 16B clears
    int cblk = (nclr + 1023) / 1024;         // 3125 clear blocks (= tblk/2)
    prep1<<<tblk + cblk, 1024, 0, stream>>>(verts, vT, ell, V, nclr);

    fill_cas<<<(E + 1023) / 1024, 1024, 0, stream>>>(faces, ell, E);

    gather_t<<<V / 32, 1024, 0, stream>>>(vT, ell, out, V);
}